// Round 10
// baseline (253.187 us; speedup 1.0000x reference)
//
#include <hip/hip_runtime.h>
#include <math.h>

#define N_NODES 20000
#define E_EDGES 320000
#define E_TOT   (E_EDGES + N_NODES)
#define IN_DIM  384
#define DIM     256
#define LAYERS  3
#define NEG_SLOPE 0.2f
#define LN_EPS 1e-5f

typedef unsigned short u16;
typedef unsigned int u32;
typedef __attribute__((ext_vector_type(8))) short short8;
typedef __attribute__((ext_vector_type(8))) __bf16 bf16x8;
typedef __attribute__((ext_vector_type(4))) float f32x4;

__device__ inline u16 f2bf(float f) {
    u32 u = __builtin_bit_cast(u32, f);
    return (u16)((u + 0x7fffu + ((u >> 16) & 1u)) >> 16);
}
__device__ inline float bf2f(u16 s) {
    u32 u = (u32)s << 16;
    return __builtin_bit_cast(float, u);
}

// float2 helpers — packed-math friendly
__device__ inline float2 f2add(float2 a, float2 b) { return make_float2(a.x + b.x, a.y + b.y); }
__device__ inline float2 f2mul(float2 a, float2 b) { return make_float2(a.x * b.x, a.y * b.y); }
__device__ inline float2 f2fma(float2 a, float2 b, float2 c) {
    return make_float2(fmaf(a.x, b.x, c.x), fmaf(a.y, b.y, c.y));
}
__device__ inline float2 f2max(float2 a, float2 b) {
    return make_float2(fmaxf(a.x, b.x), fmaxf(a.y, b.y));
}

// DPP butterfly add within 16-lane rows (bit-identical to shfl tree; r7-verified).
template <int CTRL>
__device__ inline float dpp_add(float v) {
    int x = __builtin_bit_cast(int, v);
    int y = __builtin_amdgcn_update_dpp(0, x, CTRL, 0xF, 0xF, true);
    return v + __builtin_bit_cast(float, y);
}
__device__ inline float red16(float p) {
    p = dpp_add<0xB1>(p);    // xor1
    p = dpp_add<0x4E>(p);    // xor2
    p = dpp_add<0x141>(p);   // row_half_mirror = xor4 (post quad-uniform)
    p = dpp_add<0x140>(p);   // row_mirror      = xor8 (post 8-uniform)
    return p;
}
__device__ inline float red64(float v) {
    v = red16(v);
    v += __shfl_xor(v, 16);
    v += __shfl_xor(v, 32);
    return v;
}

__device__ inline f32x4 mfma_bf16(short8 a, short8 b, f32x4 c) {
    return __builtin_amdgcn_mfma_f32_16x16x32_bf16(
        __builtin_bit_cast(bf16x8, a), __builtin_bit_cast(bf16x8, b), c, 0, 0, 0);
}

__device__ inline void gl_lds16(const u16* g, u16* l) {
    __builtin_amdgcn_global_load_lds(
        (const __attribute__((address_space(1))) u32*)g,
        (__attribute__((address_space(3))) u32*)l, 16, 0, 0);
}

#define W_IN_ELEMS (IN_DIM * DIM)
#define W_LR_ELEMS (2 * DIM * DIM)
#define W_TOT (W_IN_ELEMS + LAYERS * W_LR_ELEMS)

// ---------------- fast zero (rocclr fillBuffer was 40us/call) -----------------
__global__ void zero_kernel(int4* __restrict__ p, int n16) {
    int i = blockIdx.x * 256 + threadIdx.x;
    if (i < n16) p[i] = make_int4(0, 0, 0, 0);
}

// ---------------- fused prep: degree count + x->bf16 + weight transpose/convert ----
#define N4X (N_NODES * IN_DIM / 4)
__global__ void prep_kernel(const int* __restrict__ ei, int* __restrict__ counts,
                            const float* __restrict__ x, u16* __restrict__ x_bf,
                            const float* __restrict__ w_in, const float* __restrict__ wl,
                            const float* __restrict__ wr, u16* __restrict__ w_out) {
    int tid = blockIdx.x * 256 + threadIdx.x;
    if (tid < E_TOT) {
        int d = (tid < E_EDGES) ? ei[E_EDGES + tid] : (tid - E_EDGES);
        atomicAdd(&counts[d], 1);
        return;
    }
    tid -= E_TOT;
    if (tid < N4X) {
        float4 v = reinterpret_cast<const float4*>(x)[tid];
        reinterpret_cast<ushort4*>(x_bf)[tid] =
            make_ushort4(f2bf(v.x), f2bf(v.y), f2bf(v.z), f2bf(v.w));
        return;
    }
    tid -= N4X;
    if (tid < W_TOT) {
        float v;
        if (tid < W_IN_ELEMS) {
            int n = tid / IN_DIM, k = tid % IN_DIM;
            v = w_in[k * DIM + n];
        } else {
            int j = tid - W_IN_ELEMS;
            int l = j / W_LR_ELEMS;
            int r = j % W_LR_ELEMS;
            int n = r >> 8, k = r & 255;
            const float* W = (n < DIM) ? wl : wr;
            v = W[l * DIM * DIM + k * DIM + (n & 255)];
        }
        w_out[tid] = f2bf(v);
    }
}

// ---------------- CSR scan + scatter ----------------
__global__ __launch_bounds__(1024) void scan_kernel(const int* __restrict__ counts,
                                                    int* __restrict__ row_ptr) {
    __shared__ int sums[1024];
    const int t = threadIdx.x;
    const int CH = (N_NODES + 1023) / 1024;
    int base = t * CH;
    int local = 0;
    for (int i = 0; i < CH; ++i) {
        int idx = base + i;
        if (idx < N_NODES) local += counts[idx];
    }
    sums[t] = local;
    __syncthreads();
    for (int off = 1; off < 1024; off <<= 1) {
        int v = (t >= off) ? sums[t - off] : 0;
        __syncthreads();
        sums[t] += v;
        __syncthreads();
    }
    int run = (t == 0) ? 0 : sums[t - 1];
    for (int i = 0; i < CH; ++i) {
        int idx = base + i;
        if (idx < N_NODES) { row_ptr[idx] = run; run += counts[idx]; }
    }
    if (t == 1023) row_ptr[N_NODES] = sums[1023];
}

__global__ void scatter_kernel(const int* __restrict__ ei, const int* __restrict__ row_ptr,
                               int* __restrict__ cursor, int* __restrict__ csr_src) {
    int e = blockIdx.x * 256 + threadIdx.x;
    if (e >= E_TOT) return;
    int s, d;
    if (e < E_EDGES) { s = ei[e]; d = ei[E_EDGES + e]; }
    else { s = e - E_EDGES; d = s; }
    int pos = row_ptr[d] + atomicAdd(&cursor[d], 1);
    csr_src[pos] = s;
}

// ---------------- bf16 MFMA GEMM, 128x128 tile, BK=64, double-buffered, XCD-grouped
// C = A @ B^T (B as [Ncols][K]). SPLIT=false: one output (ldc=256, +bias opt).
// SPLIT=true: cols 0-255 -> C0 [M][256], cols 256-511 -> C1 [M][256].
#define BM 128
#define BN 128
#define BK 64
template <int K, bool BIAS, bool SPLIT, int NX, int NTOT>
__global__ __launch_bounds__(256) void gemm_mfma(
    const u16* __restrict__ A, const u16* __restrict__ B,
    const float* __restrict__ bias, u16* __restrict__ C0, u16* __restrict__ C1,
    int M) {
    __shared__ u16 lds[2][2][BM * BK];
    const int tid = threadIdx.x;
    const int w = tid >> 6, lane = tid & 63;
    const int wm = w >> 1, wn = w & 1;

    int lin = blockIdx.y * NX + blockIdx.x;
    constexpr int q8 = NTOT >> 3, r8 = NTOT & 7;
    int k8 = lin & 7, j8 = lin >> 3;
    int bid2 = k8 * q8 + min(k8, r8) + j8;     // bijective XCD remap (m204)
    const int bm = (bid2 / NX) * BM, bn = (bid2 % NX) * BN;

    u16* outp = (!SPLIT || bn < 256) ? C0 : C1;
    const int coff = (!SPLIT || bn < 256) ? 0 : 256;

    const int fr = lane & 15, q = lane >> 4;
    f32x4 acc[4][4] = {};

    const int s_row = tid >> 3, s_blk = tid & 7;
    constexpr int NT = K / BK;

#pragma unroll
    for (int i = 0; i < 4; ++i) {
        int row = i * 32 + s_row;
        int gcol = ((s_blk ^ (row & 7)) << 3);
        int base = (i * 256 + (tid & ~63)) << 3;
        int ra = min(bm + row, M - 1);
        gl_lds16(A + (size_t)ra * K + gcol, &lds[0][0][base]);
        gl_lds16(B + (size_t)(bn + row) * K + gcol, &lds[0][1][base]);
    }
    __syncthreads();

    for (int t = 0; t < NT; ++t) {
        const int p = t & 1;
        if (t + 1 < NT) {
            const int k0 = (t + 1) * BK;
#pragma unroll
            for (int i = 0; i < 4; ++i) {
                int row = i * 32 + s_row;
                int gcol = ((s_blk ^ (row & 7)) << 3);
                int base = (i * 256 + (tid & ~63)) << 3;
                int ra = min(bm + row, M - 1);
                gl_lds16(A + (size_t)ra * K + k0 + gcol, &lds[p ^ 1][0][base]);
                gl_lds16(B + (size_t)(bn + row) * K + k0 + gcol, &lds[p ^ 1][1][base]);
            }
        }
        short8 a_f[2][4], b_f[2][4];
#pragma unroll
        for (int kk = 0; kk < 2; ++kk) {
#pragma unroll
            for (int mi = 0; mi < 4; ++mi) {
                int row = wm * 64 + mi * 16 + fr;
                a_f[kk][mi] = *reinterpret_cast<const short8*>(
                    &lds[p][0][row * BK + ((((kk << 2) + q) ^ (row & 7)) << 3)]);
            }
#pragma unroll
            for (int ni = 0; ni < 4; ++ni) {
                int row = wn * 64 + ni * 16 + fr;
                b_f[kk][ni] = *reinterpret_cast<const short8*>(
                    &lds[p][1][row * BK + ((((kk << 2) + q) ^ (row & 7)) << 3)]);
            }
        }
#pragma unroll
        for (int kk = 0; kk < 2; ++kk)
#pragma unroll
            for (int mi = 0; mi < 4; ++mi)
#pragma unroll
                for (int ni = 0; ni < 4; ++ni)
                    acc[mi][ni] = mfma_bf16(a_f[kk][mi], b_f[kk][ni], acc[mi][ni]);
        __syncthreads();
    }

#pragma unroll
    for (int mi = 0; mi < 4; ++mi) {
#pragma unroll
        for (int r = 0; r < 4; ++r) {
            int row = bm + wm * 64 + mi * 16 + q * 4 + r;
            if (row >= M) continue;
#pragma unroll
            for (int ni = 0; ni < 4; ++ni) {
                int col = bn + wn * 64 + ni * 16 + fr;
                float v = acc[mi][ni][r];
                if (BIAS) v += bias[col];
                outp[(size_t)row * 256 + (col - coff)] = f2bf(v);
            }
        }
    }
}

// ---------------- GATv2 edge aggregation + bias + LN + residual (bf16 h) -------
// FOUR waves per node (edge quarter split, LDS combine): chain length d/4.
// Diagnostic lever: TLP without VGPR cost (ILP variants regressed r6/r7).
// DPP red16; no-max softmax (validated r4-r9). One node per 256-thread block.
template <bool LAST>
__global__ __launch_bounds__(256) void gat_edge(const u16* __restrict__ xl_bf,
                                                const u16* __restrict__ xr_bf,
                                                const int* __restrict__ row_ptr,
                                                const int* __restrict__ csr_src,
                                                const float* __restrict__ att,
                                                const float* __restrict__ bias,
                                                const float* __restrict__ ln_g,
                                                const float* __restrict__ ln_b,
                                                u16* __restrict__ h_bf,
                                                float* __restrict__ out) {
    __shared__ float comb[3][64][5];
    const int wave = threadIdx.x >> 6;
    const int lane = threadIdx.x & 63;
    const int node = blockIdx.x;
    const int c4 = lane << 2;

    const float4 a4 = *reinterpret_cast<const float4*>(att + c4);
    const float2 a01 = make_float2(a4.x, a4.y), a23 = make_float2(a4.z, a4.w);
    const ushort4 uxr = *reinterpret_cast<const ushort4*>(xr_bf + (size_t)node * DIM + c4);
    const float2 xr01 = make_float2(bf2f(uxr.x), bf2f(uxr.y));
    const float2 xr23 = make_float2(bf2f(uxr.z), bf2f(uxr.w));
    const float2 k02 = make_float2(NEG_SLOPE, NEG_SLOPE);

    const int e0 = row_ptr[node];
    const int d = row_ptr[node + 1] - e0;
    const int dq = d >> 2, dr = d & 3;
    const int me0 = e0 + wave * dq + min(wave, dr);
    const int md  = dq + (wave < dr ? 1 : 0);

    float sA = 0.f, sB = 0.f;
    float2 aA01 = make_float2(0.f, 0.f), aA23 = aA01, aB01 = aA01, aB23 = aA01;

    int e = 0;
    for (; e + 1 < md; e += 2) {
        int srcA = csr_src[me0 + e], srcB = csr_src[me0 + e + 1];
        ushort4 ua = *reinterpret_cast<const ushort4*>(xl_bf + (size_t)srcA * DIM + c4);
        ushort4 ub = *reinterpret_cast<const ushort4*>(xl_bf + (size_t)srcB * DIM + c4);

        float2 va01 = make_float2(bf2f(ua.x), bf2f(ua.y));
        float2 va23 = make_float2(bf2f(ua.z), bf2f(ua.w));
        float2 vb01 = make_float2(bf2f(ub.x), bf2f(ub.y));
        float2 vb23 = make_float2(bf2f(ub.z), bf2f(ub.w));

        float2 ta01 = f2add(va01, xr01), ta23 = f2add(va23, xr23);
        float2 la01 = f2max(ta01, f2mul(ta01, k02));
        float2 la23 = f2max(ta23, f2mul(ta23, k02));
        float2 dda = f2fma(la01, a01, f2mul(la23, a23));
        float pA = red16(dda.x + dda.y);

        float2 tb01 = f2add(vb01, xr01), tb23 = f2add(vb23, xr23);
        float2 lb01 = f2max(tb01, f2mul(tb01, k02));
        float2 lb23 = f2max(tb23, f2mul(tb23, k02));
        float2 ddb = f2fma(lb01, a01, f2mul(lb23, a23));
        float pB = red16(ddb.x + ddb.y);

        float peA = __expf(pA);
        float peB = __expf(pB);
        sA += peA; sB += peB;
        float2 peA2 = make_float2(peA, peA), peB2 = make_float2(peB, peB);
        aA01 = f2fma(peA2, va01, aA01);
        aA23 = f2fma(peA2, va23, aA23);
        aB01 = f2fma(peB2, vb01, aB01);
        aB23 = f2fma(peB2, vb23, aB23);
    }
    if (e < md) {
        int srcA = csr_src[me0 + e];
        ushort4 ua = *reinterpret_cast<const ushort4*>(xl_bf + (size_t)srcA * DIM + c4);
        float2 va01 = make_float2(bf2f(ua.x), bf2f(ua.y));
        float2 va23 = make_float2(bf2f(ua.z), bf2f(ua.w));
        float2 ta01 = f2add(va01, xr01), ta23 = f2add(va23, xr23);
        float2 la01 = f2max(ta01, f2mul(ta01, k02));
        float2 la23 = f2max(ta23, f2mul(ta23, k02));
        float2 dda = f2fma(la01, a01, f2mul(la23, a23));
        float pA = red16(dda.x + dda.y);
        float peA = __expf(pA);
        sA += peA;
        float2 peA2 = make_float2(peA, peA);
        aA01 = f2fma(peA2, va01, aA01);
        aA23 = f2fma(peA2, va23, aA23);
    }

    float s = sA + sB;
    float2 acc01 = f2add(aA01, aB01), acc23 = f2add(aA23, aB23);

    if (wave) {
        comb[wave - 1][lane][0] = s;
        comb[wave - 1][lane][1] = acc01.x;
        comb[wave - 1][lane][2] = acc01.y;
        comb[wave - 1][lane][3] = acc23.x;
        comb[wave - 1][lane][4] = acc23.y;
    }
    __syncthreads();
    if (wave) return;

#pragma unroll
    for (int wv = 0; wv < 3; ++wv) {
        s += comb[wv][lane][0];
        acc01.x += comb[wv][lane][1];
        acc01.y += comb[wv][lane][2];
        acc23.x += comb[wv][lane][3];
        acc23.y += comb[wv][lane][4];
    }

    float inv = 1.f / (s + 1e-16f);
    float2 inv2 = make_float2(inv, inv);
    const float4 b4 = *reinterpret_cast<const float4*>(bias + c4);
    float2 o01 = f2fma(acc01, inv2, make_float2(b4.x, b4.y));
    float2 o23 = f2fma(acc23, inv2, make_float2(b4.z, b4.w));

    float lsum = red64(o01.x + o01.y + o23.x + o23.y);
    float lsq  = red64(o01.x * o01.x + o01.y * o01.y + o23.x * o23.x + o23.y * o23.y);
    float mu = lsum * (1.f / 256.f);
    float var = lsq * (1.f / 256.f) - mu * mu;
    float rstd = rsqrtf(var + LN_EPS);
    const float4 g4  = *reinterpret_cast<const float4*>(ln_g + c4);
    const float4 lb4 = *reinterpret_cast<const float4*>(ln_b + c4);
    float2 mu2 = make_float2(-mu, -mu), rstd2 = make_float2(rstd, rstd);

    const ushort4 uh = *reinterpret_cast<const ushort4*>(h_bf + (size_t)node * DIM + c4);
    float2 h01 = make_float2(bf2f(uh.x), bf2f(uh.y));
    float2 h23 = make_float2(bf2f(uh.z), bf2f(uh.w));
    float2 n01 = f2fma(f2mul(f2add(o01, mu2), rstd2), make_float2(g4.x, g4.y),
                       make_float2(lb4.x, lb4.y));
    float2 n23 = f2fma(f2mul(f2add(o23, mu2), rstd2), make_float2(g4.z, g4.w),
                       make_float2(lb4.z, lb4.w));
    h01 = f2add(h01, n01);
    h23 = f2add(h23, n23);

    if (LAST) {
        float nsq = red64(h01.x * h01.x + h01.y * h01.y + h23.x * h23.x + h23.y * h23.y);
        float ninv = 1.f / fmaxf(sqrtf(nsq), 1e-12f);
        float4 o = make_float4(h01.x * ninv, h01.y * ninv, h23.x * ninv, h23.y * ninv);
        *reinterpret_cast<float4*>(out + (size_t)node * DIM + c4) = o;
    } else {
        *reinterpret_cast<ushort4*>(h_bf + (size_t)node * DIM + c4) =
            make_ushort4(f2bf(h01.x), f2bf(h01.y), f2bf(h23.x), f2bf(h23.y));
    }
}

extern "C" void kernel_launch(void* const* d_in, const int* in_sizes, int n_in,
                              void* d_out, int out_size, void* d_ws, size_t ws_size,
                              hipStream_t stream) {
    const float* x    = (const float*)d_in[0];
    const int*   ei   = (const int*)d_in[1];
    const float* w_in = (const float*)d_in[2];
    const float* b_in = (const float*)d_in[3];
    const float* wl   = (const float*)d_in[4];
    const float* wr   = (const float*)d_in[5];
    const float* att  = (const float*)d_in[6];
    const float* bias = (const float*)d_in[7];
    const float* ln_g = (const float*)d_in[8];
    const float* ln_b = (const float*)d_in[9];

    char* p = (char*)d_ws;
    u16*   h_bf  = (u16*)p;               p += (size_t)N_NODES * DIM * 2;   // 10.24 MB
    u16*   xl_bf = (u16*)p;               p += (size_t)N_NODES * DIM * 2;   // 10.24 MB
    u16*   xr_bf = (u16*)p;               p += (size_t)N_NODES * DIM * 2;   // 10.24 MB
    u16*   w_bf  = (u16*)p;               p += (size_t)W_TOT * 2;           // ~1 MB
    int* row_ptr = (int*)p;               p += (N_NODES + 1) * 4;
    int* counts  = (int*)p;               p += N_NODES * 4;
    int* cursor  = (int*)p;               p += N_NODES * 4;
    int* csr_src = (int*)p;               p += E_TOT * 4;
    u16* x_bf    = (u16*)p;               // N x IN_DIM bf16 (15.36 MB)

    zero_kernel<<<(2 * N_NODES / 4 + 255) / 256, 256, 0, stream>>>(
        (int4*)counts, 2 * N_NODES / 4);
    {
        int total = E_TOT + N4X + W_TOT;
        prep_kernel<<<(total + 255) / 256, 256, 0, stream>>>(
            ei, counts, x, x_bf, w_in, wl, wr, w_bf);
    }
    scan_kernel<<<1, 1024, 0, stream>>>(counts, row_ptr);
    scatter_kernel<<<(E_TOT + 255) / 256, 256, 0, stream>>>(ei, row_ptr, cursor, csr_src);

    constexpr int NYT = (N_NODES + BM - 1) / BM;     // 157
    gemm_mfma<IN_DIM, true, false, 2, 2 * NYT><<<dim3(2, NYT), 256, 0, stream>>>(
        x_bf, w_bf, b_in, h_bf, nullptr, N_NODES);

    for (int l = 0; l < LAYERS; ++l) {
        const u16* wlr = w_bf + W_IN_ELEMS + (size_t)l * W_LR_ELEMS;
        gemm_mfma<DIM, false, true, 4, 4 * NYT><<<dim3(4, NYT), 256, 0, stream>>>(
            h_bf, wlr, nullptr, xl_bf, xr_bf, N_NODES);
        if (l < LAYERS - 1) {
            gat_edge<false><<<N_NODES, 256, 0, stream>>>(
                xl_bf, xr_bf, row_ptr, csr_src,
                att + (size_t)l * DIM, bias + (size_t)l * DIM,
                ln_g + (size_t)l * DIM, ln_b + (size_t)l * DIM,
                h_bf, nullptr);
        } else {
            gat_edge<true><<<N_NODES, 256, 0, stream>>>(
                xl_bf, xr_bf, row_ptr, csr_src,
                att + (size_t)l * DIM, bias + (size_t)l * DIM,
                ln_g + (size_t)l * DIM, ln_b + (size_t)l * DIM,
                h_bf, (float*)d_out);
        }
    }
}

// Round 11
// 234.577 us; speedup vs baseline: 1.0793x; 1.0793x over previous
//
#include <hip/hip_runtime.h>
#include <math.h>

#define N_NODES 20000
#define E_EDGES 320000
#define E_TOT   (E_EDGES + N_NODES)
#define IN_DIM  384
#define DIM     256
#define LAYERS  3
#define NEG_SLOPE 0.2f
#define LN_EPS 1e-5f
#define L2E 1.4426950408889634f

typedef unsigned short u16;
typedef unsigned int u32;
typedef __attribute__((ext_vector_type(8))) short short8;
typedef __attribute__((ext_vector_type(8))) __bf16 bf16x8;
typedef __attribute__((ext_vector_type(4))) float f32x4;

__device__ inline u16 f2bf(float f) {
    u32 u = __builtin_bit_cast(u32, f);
    return (u16)((u + 0x7fffu + ((u >> 16) & 1u)) >> 16);
}
__device__ inline float bf2f(u16 s) {
    u32 u = (u32)s << 16;
    return __builtin_bit_cast(float, u);
}

// float2 helpers — packed-math friendly
__device__ inline float2 f2add(float2 a, float2 b) { return make_float2(a.x + b.x, a.y + b.y); }
__device__ inline float2 f2mul(float2 a, float2 b) { return make_float2(a.x * b.x, a.y * b.y); }
__device__ inline float2 f2fma(float2 a, float2 b, float2 c) {
    return make_float2(fmaf(a.x, b.x, c.x), fmaf(a.y, b.y, c.y));
}
__device__ inline float2 f2max(float2 a, float2 b) {
    return make_float2(fmaxf(a.x, b.x), fmaxf(a.y, b.y));
}

// DPP butterfly add within 16-lane rows (bit-identical to shfl tree; r7-verified).
template <int CTRL>
__device__ inline float dpp_add(float v) {
    int x = __builtin_bit_cast(int, v);
    int y = __builtin_amdgcn_update_dpp(0, x, CTRL, 0xF, 0xF, true);
    return v + __builtin_bit_cast(float, y);
}
__device__ inline float red16(float p) {
    p = dpp_add<0xB1>(p);    // xor1
    p = dpp_add<0x4E>(p);    // xor2
    p = dpp_add<0x141>(p);   // row_half_mirror = xor4 (post quad-uniform)
    p = dpp_add<0x140>(p);   // row_mirror      = xor8 (post 8-uniform)
    return p;
}
__device__ inline float red64(float v) {
    v = red16(v);
    v += __shfl_xor(v, 16);
    v += __shfl_xor(v, 32);
    return v;
}

__device__ inline f32x4 mfma_bf16(short8 a, short8 b, f32x4 c) {
    return __builtin_amdgcn_mfma_f32_16x16x32_bf16(
        __builtin_bit_cast(bf16x8, a), __builtin_bit_cast(bf16x8, b), c, 0, 0, 0);
}

__device__ inline void gl_lds16(const u16* g, u16* l) {
    __builtin_amdgcn_global_load_lds(
        (const __attribute__((address_space(1))) u32*)g,
        (__attribute__((address_space(3))) u32*)l, 16, 0, 0);
}

#define W_IN_ELEMS (IN_DIM * DIM)
#define W_LR_ELEMS (2 * DIM * DIM)
#define W_TOT (W_IN_ELEMS + LAYERS * W_LR_ELEMS)

// ---------------- fast zero (rocclr fillBuffer was 40us/call) -----------------
__global__ void zero_kernel(int4* __restrict__ p, int n16) {
    int i = blockIdx.x * 256 + threadIdx.x;
    if (i < n16) p[i] = make_int4(0, 0, 0, 0);
}

// ---------------- fused prep: degree count + x->bf16 + weight transpose/convert ----
#define N4X (N_NODES * IN_DIM / 4)
__global__ void prep_kernel(const int* __restrict__ ei, int* __restrict__ counts,
                            const float* __restrict__ x, u16* __restrict__ x_bf,
                            const float* __restrict__ w_in, const float* __restrict__ wl,
                            const float* __restrict__ wr, u16* __restrict__ w_out) {
    int tid = blockIdx.x * 256 + threadIdx.x;
    if (tid < E_TOT) {
        int d = (tid < E_EDGES) ? ei[E_EDGES + tid] : (tid - E_EDGES);
        atomicAdd(&counts[d], 1);
        return;
    }
    tid -= E_TOT;
    if (tid < N4X) {
        float4 v = reinterpret_cast<const float4*>(x)[tid];
        reinterpret_cast<ushort4*>(x_bf)[tid] =
            make_ushort4(f2bf(v.x), f2bf(v.y), f2bf(v.z), f2bf(v.w));
        return;
    }
    tid -= N4X;
    if (tid < W_TOT) {
        float v;
        if (tid < W_IN_ELEMS) {
            int n = tid / IN_DIM, k = tid % IN_DIM;
            v = w_in[k * DIM + n];
        } else {
            int j = tid - W_IN_ELEMS;
            int l = j / W_LR_ELEMS;
            int r = j % W_LR_ELEMS;
            int n = r >> 8, k = r & 255;
            const float* W = (n < DIM) ? wl : wr;
            v = W[l * DIM * DIM + k * DIM + (n & 255)];
        }
        w_out[tid] = f2bf(v);
    }
}

// ---------------- CSR scan ----------------
__global__ __launch_bounds__(1024) void scan_kernel(const int* __restrict__ counts,
                                                    int* __restrict__ row_ptr) {
    __shared__ int sums[1024];
    const int t = threadIdx.x;
    const int CH = (N_NODES + 1023) / 1024;
    int base = t * CH;
    int local = 0;
    for (int i = 0; i < CH; ++i) {
        int idx = base + i;
        if (idx < N_NODES) local += counts[idx];
    }
    sums[t] = local;
    __syncthreads();
    for (int off = 1; off < 1024; off <<= 1) {
        int v = (t >= off) ? sums[t - off] : 0;
        __syncthreads();
        sums[t] += v;
        __syncthreads();
    }
    int run = (t == 0) ? 0 : sums[t - 1];
    for (int i = 0; i < CH; ++i) {
        int idx = base + i;
        if (idx < N_NODES) { row_ptr[idx] = run; run += counts[idx]; }
    }
    if (t == 1023) row_ptr[N_NODES] = sums[1023];
}

// ---------------- bf16 MFMA GEMM, 128x128 tile, BK=64, double-buffered, XCD-grouped
// C = A @ B^T (B as [Ncols][K]). SPLIT=false: one output (ldc=256, +bias opt).
// SPLIT=true: cols 0-255 -> C0, cols 256-511 -> C1 (each [M][256]).
// FUSED: grid rows >= NTOT/NX run the CSR scatter instead (independent work
// hidden under the GEMM; saves one dispatch + ~8us of serial time).
#define BM 128
#define BN 128
#define BK 64
template <int K, bool BIAS, bool SPLIT, bool FUSED, int NX, int NTOT>
__global__ __launch_bounds__(256) void gemm_mfma(
    const u16* __restrict__ A, const u16* __restrict__ B,
    const float* __restrict__ bias, u16* __restrict__ C0, u16* __restrict__ C1,
    int M,
    const int* __restrict__ ei, const int* __restrict__ row_ptr,
    int* __restrict__ cursor, int* __restrict__ csr_src) {
    __shared__ u16 lds[2][2][BM * BK];
    const int tid = threadIdx.x;

    if (FUSED) {
        constexpr int gy = NTOT / NX;
        if ((int)blockIdx.y >= gy) {
            int sb = ((int)blockIdx.y - gy) * NX + (int)blockIdx.x;
            int e = sb * 256 + tid;
            if (e < E_TOT) {
                int s, dd;
                if (e < E_EDGES) { s = ei[e]; dd = ei[E_EDGES + e]; }
                else { s = e - E_EDGES; dd = s; }
                int pos = row_ptr[dd] + atomicAdd(&cursor[dd], 1);
                csr_src[pos] = s;
            }
            return;
        }
    }

    const int w = tid >> 6, lane = tid & 63;
    const int wm = w >> 1, wn = w & 1;

    int lin = blockIdx.y * NX + blockIdx.x;
    constexpr int q8 = NTOT >> 3, r8 = NTOT & 7;
    int k8 = lin & 7, j8 = lin >> 3;
    int bid2 = k8 * q8 + min(k8, r8) + j8;     // bijective XCD remap (m204)
    const int bm = (bid2 / NX) * BM, bn = (bid2 % NX) * BN;

    u16* outp = (!SPLIT || bn < 256) ? C0 : C1;
    const int coff = (!SPLIT || bn < 256) ? 0 : 256;

    const int fr = lane & 15, q = lane >> 4;
    f32x4 acc[4][4] = {};

    const int s_row = tid >> 3, s_blk = tid & 7;
    constexpr int NT = K / BK;

#pragma unroll
    for (int i = 0; i < 4; ++i) {
        int row = i * 32 + s_row;
        int gcol = ((s_blk ^ (row & 7)) << 3);
        int base = (i * 256 + (tid & ~63)) << 3;
        int ra = min(bm + row, M - 1);
        gl_lds16(A + (size_t)ra * K + gcol, &lds[0][0][base]);
        gl_lds16(B + (size_t)(bn + row) * K + gcol, &lds[0][1][base]);
    }
    __syncthreads();

    for (int t = 0; t < NT; ++t) {
        const int p = t & 1;
        if (t + 1 < NT) {
            const int k0 = (t + 1) * BK;
#pragma unroll
            for (int i = 0; i < 4; ++i) {
                int row = i * 32 + s_row;
                int gcol = ((s_blk ^ (row & 7)) << 3);
                int base = (i * 256 + (tid & ~63)) << 3;
                int ra = min(bm + row, M - 1);
                gl_lds16(A + (size_t)ra * K + k0 + gcol, &lds[p ^ 1][0][base]);
                gl_lds16(B + (size_t)(bn + row) * K + k0 + gcol, &lds[p ^ 1][1][base]);
            }
        }
        short8 a_f[2][4], b_f[2][4];
#pragma unroll
        for (int kk = 0; kk < 2; ++kk) {
#pragma unroll
            for (int mi = 0; mi < 4; ++mi) {
                int row = wm * 64 + mi * 16 + fr;
                a_f[kk][mi] = *reinterpret_cast<const short8*>(
                    &lds[p][0][row * BK + ((((kk << 2) + q) ^ (row & 7)) << 3)]);
            }
#pragma unroll
            for (int ni = 0; ni < 4; ++ni) {
                int row = wn * 64 + ni * 16 + fr;
                b_f[kk][ni] = *reinterpret_cast<const short8*>(
                    &lds[p][1][row * BK + ((((kk << 2) + q) ^ (row & 7)) << 3)]);
            }
        }
#pragma unroll
        for (int kk = 0; kk < 2; ++kk)
#pragma unroll
            for (int mi = 0; mi < 4; ++mi)
#pragma unroll
                for (int ni = 0; ni < 4; ++ni)
                    acc[mi][ni] = mfma_bf16(a_f[kk][mi], b_f[kk][ni], acc[mi][ni]);
        __syncthreads();
    }

#pragma unroll
    for (int mi = 0; mi < 4; ++mi) {
#pragma unroll
        for (int r = 0; r < 4; ++r) {
            int row = bm + wm * 64 + mi * 16 + q * 4 + r;
            if (row >= M) continue;
#pragma unroll
            for (int ni = 0; ni < 4; ++ni) {
                int col = bn + wn * 64 + ni * 16 + fr;
                float v = acc[mi][ni][r];
                if (BIAS) v += bias[col];
                outp[(size_t)row * 256 + (col - coff)] = f2bf(v);
            }
        }
    }
}

// ---------------- GATv2 edge aggregation + bias + LN + residual (bf16 h) -------
// TWO waves per node (r8/r10 A/B: 2-wave optimum; 4-wave regressed on per-wave
// fixed costs). DPP red16; no-max softmax with log2e folded into att ->
// single v_exp_f32 per edge. bf16 residual h. Validated r4-r10.
template <bool LAST>
__global__ __launch_bounds__(256) void gat_edge(const u16* __restrict__ xl_bf,
                                                const u16* __restrict__ xr_bf,
                                                const int* __restrict__ row_ptr,
                                                const int* __restrict__ csr_src,
                                                const float* __restrict__ att,
                                                const float* __restrict__ bias,
                                                const float* __restrict__ ln_g,
                                                const float* __restrict__ ln_b,
                                                u16* __restrict__ h_bf,
                                                float* __restrict__ out) {
    __shared__ float comb[2][64][6];
    const int wave = threadIdx.x >> 6;
    const int lane = threadIdx.x & 63;
    const int nsub = wave >> 1;
    const int half = wave & 1;
    const int node = blockIdx.x * 2 + nsub;
    const int c4 = lane << 2;

    const float4 a4r = *reinterpret_cast<const float4*>(att + c4);
    // fold log2(e) into att: softmax ratios unchanged, exp -> raw v_exp_f32
    const float2 a01 = make_float2(a4r.x * L2E, a4r.y * L2E);
    const float2 a23 = make_float2(a4r.z * L2E, a4r.w * L2E);
    const ushort4 uxr = *reinterpret_cast<const ushort4*>(xr_bf + (size_t)node * DIM + c4);
    const float2 xr01 = make_float2(bf2f(uxr.x), bf2f(uxr.y));
    const float2 xr23 = make_float2(bf2f(uxr.z), bf2f(uxr.w));
    const float2 k02 = make_float2(NEG_SLOPE, NEG_SLOPE);

    const int e0 = row_ptr[node];
    const int d = row_ptr[node + 1] - e0;
    const int dh = d >> 1;
    const int me0 = e0 + (half ? dh : 0);
    const int md  = half ? (d - dh) : dh;

    float sA = 0.f, sB = 0.f;
    float2 aA01 = make_float2(0.f, 0.f), aA23 = aA01, aB01 = aA01, aB23 = aA01;

    int e = 0;
    for (; e + 1 < md; e += 2) {
        int srcA = csr_src[me0 + e], srcB = csr_src[me0 + e + 1];
        ushort4 ua = *reinterpret_cast<const ushort4*>(xl_bf + (size_t)srcA * DIM + c4);
        ushort4 ub = *reinterpret_cast<const ushort4*>(xl_bf + (size_t)srcB * DIM + c4);

        float2 va01 = make_float2(bf2f(ua.x), bf2f(ua.y));
        float2 va23 = make_float2(bf2f(ua.z), bf2f(ua.w));
        float2 vb01 = make_float2(bf2f(ub.x), bf2f(ub.y));
        float2 vb23 = make_float2(bf2f(ub.z), bf2f(ub.w));

        float2 ta01 = f2add(va01, xr01), ta23 = f2add(va23, xr23);
        float2 la01 = f2max(ta01, f2mul(ta01, k02));
        float2 la23 = f2max(ta23, f2mul(ta23, k02));
        float2 dda = f2fma(la01, a01, f2mul(la23, a23));
        float pA = red16(dda.x + dda.y);

        float2 tb01 = f2add(vb01, xr01), tb23 = f2add(vb23, xr23);
        float2 lb01 = f2max(tb01, f2mul(tb01, k02));
        float2 lb23 = f2max(tb23, f2mul(tb23, k02));
        float2 ddb = f2fma(lb01, a01, f2mul(lb23, a23));
        float pB = red16(ddb.x + ddb.y);

        float peA = __builtin_amdgcn_exp2f(pA);
        float peB = __builtin_amdgcn_exp2f(pB);
        sA += peA; sB += peB;
        float2 peA2 = make_float2(peA, peA), peB2 = make_float2(peB, peB);
        aA01 = f2fma(peA2, va01, aA01);
        aA23 = f2fma(peA2, va23, aA23);
        aB01 = f2fma(peB2, vb01, aB01);
        aB23 = f2fma(peB2, vb23, aB23);
    }
    if (e < md) {
        int srcA = csr_src[me0 + e];
        ushort4 ua = *reinterpret_cast<const ushort4*>(xl_bf + (size_t)srcA * DIM + c4);
        float2 va01 = make_float2(bf2f(ua.x), bf2f(ua.y));
        float2 va23 = make_float2(bf2f(ua.z), bf2f(ua.w));
        float2 ta01 = f2add(va01, xr01), ta23 = f2add(va23, xr23);
        float2 la01 = f2max(ta01, f2mul(ta01, k02));
        float2 la23 = f2max(ta23, f2mul(ta23, k02));
        float2 dda = f2fma(la01, a01, f2mul(la23, a23));
        float pA = red16(dda.x + dda.y);
        float peA = __builtin_amdgcn_exp2f(pA);
        sA += peA;
        float2 peA2 = make_float2(peA, peA);
        aA01 = f2fma(peA2, va01, aA01);
        aA23 = f2fma(peA2, va23, aA23);
    }

    float s = sA + sB;
    float2 acc01 = f2add(aA01, aB01), acc23 = f2add(aA23, aB23);

    if (half) {
        comb[nsub][lane][0] = s;
        comb[nsub][lane][1] = acc01.x;
        comb[nsub][lane][2] = acc01.y;
        comb[nsub][lane][3] = acc23.x;
        comb[nsub][lane][4] = acc23.y;
    }
    __syncthreads();
    if (half) return;

    s += comb[nsub][lane][0];
    acc01.x += comb[nsub][lane][1];
    acc01.y += comb[nsub][lane][2];
    acc23.x += comb[nsub][lane][3];
    acc23.y += comb[nsub][lane][4];

    float inv = 1.f / (s + 1e-16f);
    float2 inv2 = make_float2(inv, inv);
    const float4 b4 = *reinterpret_cast<const float4*>(bias + c4);
    float2 o01 = f2fma(acc01, inv2, make_float2(b4.x, b4.y));
    float2 o23 = f2fma(acc23, inv2, make_float2(b4.z, b4.w));

    float lsum = red64(o01.x + o01.y + o23.x + o23.y);
    float lsq  = red64(o01.x * o01.x + o01.y * o01.y + o23.x * o23.x + o23.y * o23.y);
    float mu = lsum * (1.f / 256.f);
    float var = lsq * (1.f / 256.f) - mu * mu;
    float rstd = rsqrtf(var + LN_EPS);
    const float4 g4  = *reinterpret_cast<const float4*>(ln_g + c4);
    const float4 lb4 = *reinterpret_cast<const float4*>(ln_b + c4);
    float2 mu2 = make_float2(-mu, -mu), rstd2 = make_float2(rstd, rstd);

    const ushort4 uh = *reinterpret_cast<const ushort4*>(h_bf + (size_t)node * DIM + c4);
    float2 h01 = make_float2(bf2f(uh.x), bf2f(uh.y));
    float2 h23 = make_float2(bf2f(uh.z), bf2f(uh.w));
    float2 n01 = f2fma(f2mul(f2add(o01, mu2), rstd2), make_float2(g4.x, g4.y),
                       make_float2(lb4.x, lb4.y));
    float2 n23 = f2fma(f2mul(f2add(o23, mu2), rstd2), make_float2(g4.z, g4.w),
                       make_float2(lb4.z, lb4.w));
    h01 = f2add(h01, n01);
    h23 = f2add(h23, n23);

    if (LAST) {
        float nsq = red64(h01.x * h01.x + h01.y * h01.y + h23.x * h23.x + h23.y * h23.y);
        float ninv = 1.f / fmaxf(sqrtf(nsq), 1e-12f);
        float4 o = make_float4(h01.x * ninv, h01.y * ninv, h23.x * ninv, h23.y * ninv);
        *reinterpret_cast<float4*>(out + (size_t)node * DIM + c4) = o;
    } else {
        *reinterpret_cast<ushort4*>(h_bf + (size_t)node * DIM + c4) =
            make_ushort4(f2bf(h01.x), f2bf(h01.y), f2bf(h23.x), f2bf(h23.y));
    }
}

extern "C" void kernel_launch(void* const* d_in, const int* in_sizes, int n_in,
                              void* d_out, int out_size, void* d_ws, size_t ws_size,
                              hipStream_t stream) {
    const float* x    = (const float*)d_in[0];
    const int*   ei   = (const int*)d_in[1];
    const float* w_in = (const float*)d_in[2];
    const float* b_in = (const float*)d_in[3];
    const float* wl   = (const float*)d_in[4];
    const float* wr   = (const float*)d_in[5];
    const float* att  = (const float*)d_in[6];
    const float* bias = (const float*)d_in[7];
    const float* ln_g = (const float*)d_in[8];
    const float* ln_b = (const float*)d_in[9];

    char* p = (char*)d_ws;
    u16*   h_bf  = (u16*)p;               p += (size_t)N_NODES * DIM * 2;   // 10.24 MB
    u16*   xl_bf = (u16*)p;               p += (size_t)N_NODES * DIM * 2;   // 10.24 MB
    u16*   xr_bf = (u16*)p;               p += (size_t)N_NODES * DIM * 2;   // 10.24 MB
    u16*   w_bf  = (u16*)p;               p += (size_t)W_TOT * 2;           // ~1 MB
    int* row_ptr = (int*)p;               p += (N_NODES + 1) * 4;
    int* counts  = (int*)p;               p += N_NODES * 4;
    int* cursor  = (int*)p;               p += N_NODES * 4;
    int* csr_src = (int*)p;               p += E_TOT * 4;
    u16* x_bf    = (u16*)p;               // N x IN_DIM bf16 (15.36 MB)

    zero_kernel<<<(2 * N_NODES / 4 + 255) / 256, 256, 0, stream>>>(
        (int4*)counts, 2 * N_NODES / 4);
    {
        int total = E_TOT + N4X + W_TOT;
        prep_kernel<<<(total + 255) / 256, 256, 0, stream>>>(
            ei, counts, x, x_bf, w_in, wl, wr, w_bf);
    }
    scan_kernel<<<1, 1024, 0, stream>>>(counts, row_ptr);

    constexpr int NYT = (N_NODES + BM - 1) / BM;     // 157
    constexpr int SCAT_BLKS = (E_TOT + 255) / 256;   // 1329
    constexpr int SCAT_Y = (SCAT_BLKS + 1) / 2;      // 665

    // input projection GEMM, with the CSR scatter fused into extra grid rows
    gemm_mfma<IN_DIM, true, false, true, 2, 2 * NYT>
        <<<dim3(2, NYT + SCAT_Y), 256, 0, stream>>>(
        x_bf, w_bf, b_in, h_bf, nullptr, N_NODES, ei, row_ptr, cursor, csr_src);

    for (int l = 0; l < LAYERS; ++l) {
        const u16* wlr = w_bf + W_IN_ELEMS + (size_t)l * W_LR_ELEMS;
        gemm_mfma<DIM, false, true, false, 4, 4 * NYT><<<dim3(4, NYT), 256, 0, stream>>>(
            h_bf, wlr, nullptr, xl_bf, xr_bf, N_NODES,
            nullptr, nullptr, nullptr, nullptr);
        if (l < LAYERS - 1) {
            gat_edge<false><<<N_NODES / 2, 256, 0, stream>>>(
                xl_bf, xr_bf, row_ptr, csr_src,
                att + (size_t)l * DIM, bias + (size_t)l * DIM,
                ln_g + (size_t)l * DIM, ln_b + (size_t)l * DIM,
                h_bf, nullptr);
        } else {
            gat_edge<true><<<N_NODES / 2, 256, 0, stream>>>(
                xl_bf, xr_bf, row_ptr, csr_src,
                att + (size_t)l * DIM, bias + (size_t)l * DIM,
                ln_g + (size_t)l * DIM, ln_b + (size_t)l * DIM,
                h_bf, (float*)d_out);
        }
    }
}